// Round 4
// baseline (112.745 us; speedup 1.0000x reference)
//
#include <hip/hip_runtime.h>

// SkeletalConv: grouped Conv1d over skeleton edges, fused neighbor-mean.
// x: (16, 25, 65536) f32, W: (48, 16, 16, 3) f32, b: (48, 16) f32
// out: (16, 24, 65533) f32
// out[co,e,t] = 0.5*sum_{j,ci,k} W[2e+j,co,ci,k]*x[ci,e+j,t+k] + 0.5*(b[2e,co]+b[2e+1,co])
//
// Structure: weights in SGPRs (scalar loads, prefetched 2 p's ahead), x in
// 4 static register buffers (prefetched 3 bodies ahead ~ 1150 cyc > HBM 900),
// 8 co x 8 consecutive t accumulators per thread, nontemporal output stores.

#define CIN   16
#define NJ    25
#define LSEQ  65536
#define NE    24
#define NCO   16
#define KW    3
#define LOUTN (LSEQ - KW + 1)          // 65533
#define COPT  8
#define TPT   8
#define BLOCK 256
#define CHUNK (BLOCK * TPT)            // 2048
#define NCHUNK ((LOUTN + CHUNK - 1) / CHUNK)   // 32
#define NWREP (NE * 2 * 32 * 24)       // 36864 repacked weights
#define NBREP (NE * 2 * 8)             // 384 repacked biases

// Wr layout: [e][half][p=ci*2+j][co(8)][k(3)], 0.5 folded in.
// Br layout: [e][half][co(8)] = 0.5*(b[2e,co]+b[2e+1,co])
__global__ void repack_kernel(const float* __restrict__ W, const float* __restrict__ b,
                              float* __restrict__ Wr, float* __restrict__ Br)
{
    int idx = blockIdx.x * BLOCK + threadIdx.x;
    if (idx < NWREP) {
        int k = idx % 3;  int r = idx / 3;
        int co = r & 7;   r >>= 3;
        int p  = r & 31;  r >>= 5;
        int half = r & 1; int e = r >> 1;
        int ci = p >> 1, j = p & 1;
        Wr[idx] = 0.5f * W[((2 * e + j) * 16 + half * 8 + co) * 48 + ci * 3 + k];
    }
    if (idx < NBREP) {
        int co8 = idx & 7; int r = idx >> 3;
        int half = r & 1;  int e = r >> 1;
        int co = half * 8 + co8;
        Br[idx] = 0.5f * (b[2 * e * 16 + co] + b[(2 * e + 1) * 16 + co]);
    }
}

__global__ __launch_bounds__(BLOCK)
void skel_conv_kernel(const float* __restrict__ x,
                      const float* __restrict__ Wr,
                      const float* __restrict__ Br,
                      float* __restrict__ out)
{
    const int e    = blockIdx.y;
    const int half = blockIdx.z;                       // uniform -> scalar weight addressing
    const int t0   = blockIdx.x * CHUNK + threadIdx.x * TPT;  // 32B-aligned

    // x loads cover t0..t0+9; final float2 may poke past LSEQ on the last
    // lane of the last chunk -> clamp (garbage feeds only invalid outputs).
    const bool safe2 = (t0 + TPT + 1 <= LSEQ - 1);
    const int  o2    = safe2 ? (t0 + 8) : t0;

    const float* wbase = Wr + (size_t)((e * 2 + half) * 32) * 24;
    const float* bb    = Br + (e * 2 + half) * 8;

    float acc[COPT][TPT];
    #pragma unroll
    for (int co = 0; co < COPT; ++co) {
        float bv = bb[co];
        #pragma unroll
        for (int tt = 0; tt < TPT; ++tt) acc[co][tt] = bv;
    }

    float X0[TPT + 2], X1[TPT + 2], X2[TPT + 2], X3[TPT + 2];
    float w0[24], w1[24];

    auto loadx = [&](float* buf, int p) {
        const float* xp = x + (size_t)((p >> 1) * NJ + e + (p & 1)) * LSEQ;
        float4 a = *reinterpret_cast<const float4*>(xp + t0);
        float4 c = *reinterpret_cast<const float4*>(xp + t0 + 4);
        float2 d = *reinterpret_cast<const float2*>(xp + o2);
        buf[0] = a.x; buf[1] = a.y; buf[2] = a.z; buf[3] = a.w;
        buf[4] = c.x; buf[5] = c.y; buf[6] = c.z; buf[7] = c.w;
        buf[8] = d.x; buf[9] = d.y;
    };

    auto loadw = [&](float* wreg, int p) {
        const float* wp = wbase + p * 24;              // uniform -> s_load
        #pragma unroll
        for (int i = 0; i < 24; ++i) wreg[i] = wp[i];
    };

    auto body = [&](const float* buf, const float* w) {
        #pragma unroll
        for (int co = 0; co < COPT; ++co) {
            float a0 = w[co * 3 + 0];
            float a1 = w[co * 3 + 1];
            float a2 = w[co * 3 + 2];
            #pragma unroll
            for (int tt = 0; tt < TPT; ++tt) {
                acc[co][tt] = fmaf(a0, buf[tt],     acc[co][tt]);
                acc[co][tt] = fmaf(a1, buf[tt + 1], acc[co][tt]);
                acc[co][tt] = fmaf(a2, buf[tt + 2], acc[co][tt]);
            }
        }
    };

    loadw(w0, 0);
    loadw(w1, 1);
    loadx(X0, 0);
    loadx(X1, 1);
    loadx(X2, 2);

    #pragma unroll 1
    for (int p = 0; p < 32; p += 4) {
        loadx(X3, p + 3);                     // consumed 3 bodies later
        body(X0, w0);                         // p
        loadw(w0, p + 2);
        if (p + 4 < 32) loadx(X0, p + 4);
        body(X1, w1);                         // p+1
        loadw(w1, p + 3);
        if (p + 5 < 32) loadx(X1, p + 5);
        body(X2, w0);                         // p+2
        if (p + 4 < 32) loadw(w0, p + 4);
        if (p + 6 < 32) loadx(X2, p + 6);
        body(X3, w1);                         // p+3
        if (p + 5 < 32) loadw(w1, p + 5);
    }

    // ---- store: out[co_global, e, t] (rows 4B-aligned; nontemporal) ----
    const bool full = (t0 + TPT <= LOUTN);
    #pragma unroll
    for (int co = 0; co < COPT; ++co) {
        float* op = out + (size_t)((half * 8 + co) * NE + e) * LOUTN + t0;
        if (full) {
            #pragma unroll
            for (int tt = 0; tt < TPT; ++tt) __builtin_nontemporal_store(acc[co][tt], op + tt);
        } else {
            #pragma unroll
            for (int tt = 0; tt < TPT; ++tt)
                if (t0 + tt < LOUTN) op[tt] = acc[co][tt];
        }
    }
}

extern "C" void kernel_launch(void* const* d_in, const int* in_sizes, int n_in,
                              void* d_out, int out_size, void* d_ws, size_t ws_size,
                              hipStream_t stream)
{
    const float* x = (const float*)d_in[0];
    const float* W = (const float*)d_in[1];
    const float* b = (const float*)d_in[2];
    float* out     = (float*)d_out;

    float* Wr = (float*)d_ws;            // 36864 floats
    float* Br = Wr + NWREP;              // 384 floats

    repack_kernel<<<(NWREP + BLOCK - 1) / BLOCK, BLOCK, 0, stream>>>(W, b, Wr, Br);

    dim3 grid(NCHUNK, NE, 2);
    skel_conv_kernel<<<grid, BLOCK, 0, stream>>>(x, Wr, Br, out);
}

// Round 5
// 109.485 us; speedup vs baseline: 1.0298x; 1.0298x over previous
//
#include <hip/hip_runtime.h>

// SkeletalConv: grouped Conv1d over skeleton edges, fused neighbor-mean.
// x: (16, 25, 65536) f32, W: (48, 16, 16, 3) f32, b: (48, 16) f32
// out: (16, 24, 65533) f32
// out[co,e,t] = 0.5*sum_{j,ci,k} W[2e+j,co,ci,k]*x[ci,e+j,t+k] + 0.5*(b[2e,co]+b[2e+1,co])
//
// Structure: weights in SGPRs (scalar loads, prefetched 2 bodies ahead), x in
// 4 static register buffers (prefetched ~3 bodies ahead > HBM latency),
// 8 co x 8 consecutive t accumulators per thread, PLAIN dword stores
// (nontemporal dword stores caused 1.8x write amplification in round 4).

#define CIN   16
#define NJ    25
#define LSEQ  65536
#define NE    24
#define NCO   16
#define KW    3
#define LOUTN (LSEQ - KW + 1)          // 65533
#define COPT  8
#define TPT   8
#define BLOCK 256
#define CHUNK (BLOCK * TPT)            // 2048
#define NCHUNK ((LOUTN + CHUNK - 1) / CHUNK)   // 32
#define NWREP (NE * 2 * 32 * 24)       // 36864 repacked weights
#define NBREP (NE * 2 * 8)             // 384 repacked biases

// Wr layout: [e][half][p=ci*2+j][co(8)][k(3)], 0.5 folded in.
// Br layout: [e][half][co(8)] = 0.5*(b[2e,co]+b[2e+1,co])
__global__ void repack_kernel(const float* __restrict__ W, const float* __restrict__ b,
                              float* __restrict__ Wr, float* __restrict__ Br)
{
    int idx = blockIdx.x * BLOCK + threadIdx.x;
    if (idx < NWREP) {
        int k = idx % 3;  int r = idx / 3;
        int co = r & 7;   r >>= 3;
        int p  = r & 31;  r >>= 5;
        int half = r & 1; int e = r >> 1;
        int ci = p >> 1, j = p & 1;
        Wr[idx] = 0.5f * W[((2 * e + j) * 16 + half * 8 + co) * 48 + ci * 3 + k];
    }
    if (idx < NBREP) {
        int co8 = idx & 7; int r = idx >> 3;
        int half = r & 1;  int e = r >> 1;
        int co = half * 8 + co8;
        Br[idx] = 0.5f * (b[2 * e * 16 + co] + b[(2 * e + 1) * 16 + co]);
    }
}

__global__ __launch_bounds__(BLOCK)
void skel_conv_kernel(const float* __restrict__ x,
                      const float* __restrict__ Wr,
                      const float* __restrict__ Br,
                      float* __restrict__ out)
{
    const int e    = blockIdx.y;
    const int half = blockIdx.z;                       // uniform -> scalar weight addressing
    const int t0   = blockIdx.x * CHUNK + threadIdx.x * TPT;  // 32B-aligned

    // x loads cover t0..t0+9; final float2 may poke past LSEQ on the last
    // lane of the last chunk -> clamp (garbage feeds only invalid outputs).
    const bool safe2 = (t0 + TPT + 1 <= LSEQ - 1);
    const int  o2    = safe2 ? (t0 + 8) : t0;

    const float* wbase = Wr + (size_t)((e * 2 + half) * 32) * 24;
    const float* bb    = Br + (e * 2 + half) * 8;

    float acc[COPT][TPT];
    #pragma unroll
    for (int co = 0; co < COPT; ++co) {
        float bv = bb[co];
        #pragma unroll
        for (int tt = 0; tt < TPT; ++tt) acc[co][tt] = bv;
    }

    float X0[TPT + 2], X1[TPT + 2], X2[TPT + 2], X3[TPT + 2];
    float w0[24], w1[24];

    auto loadx = [&](float* buf, int p) {
        const float* xp = x + (size_t)((p >> 1) * NJ + e + (p & 1)) * LSEQ;
        float4 a = *reinterpret_cast<const float4*>(xp + t0);
        float4 c = *reinterpret_cast<const float4*>(xp + t0 + 4);
        float2 d = *reinterpret_cast<const float2*>(xp + o2);
        buf[0] = a.x; buf[1] = a.y; buf[2] = a.z; buf[3] = a.w;
        buf[4] = c.x; buf[5] = c.y; buf[6] = c.z; buf[7] = c.w;
        buf[8] = d.x; buf[9] = d.y;
    };

    auto loadw = [&](float* wreg, int p) {
        const float* wp = wbase + p * 24;              // uniform -> s_load
        #pragma unroll
        for (int i = 0; i < 24; ++i) wreg[i] = wp[i];
    };

    auto body = [&](const float* buf, const float* w) {
        #pragma unroll
        for (int co = 0; co < COPT; ++co) {
            float a0 = w[co * 3 + 0];
            float a1 = w[co * 3 + 1];
            float a2 = w[co * 3 + 2];
            #pragma unroll
            for (int tt = 0; tt < TPT; ++tt) {
                acc[co][tt] = fmaf(a0, buf[tt],     acc[co][tt]);
                acc[co][tt] = fmaf(a1, buf[tt + 1], acc[co][tt]);
                acc[co][tt] = fmaf(a2, buf[tt + 2], acc[co][tt]);
            }
        }
    };

    loadw(w0, 0);
    loadw(w1, 1);
    loadx(X0, 0);
    loadx(X1, 1);
    loadx(X2, 2);

    #pragma unroll 1
    for (int p = 0; p < 32; p += 4) {
        loadx(X3, p + 3);                     // consumed 3 bodies later
        body(X0, w0);                         // p
        loadw(w0, p + 2);
        if (p + 4 < 32) loadx(X0, p + 4);
        body(X1, w1);                         // p+1
        loadw(w1, p + 3);
        if (p + 5 < 32) loadx(X1, p + 5);
        body(X2, w0);                         // p+2
        if (p + 4 < 32) loadw(w0, p + 4);
        if (p + 6 < 32) loadx(X2, p + 6);
        body(X3, w1);                         // p+3
        if (p + 5 < 32) loadw(w1, p + 5);
    }

    // ---- store: out[co_global, e, t] (plain dword stores; L2 merges) ----
    const bool full = (t0 + TPT <= LOUTN);
    #pragma unroll
    for (int co = 0; co < COPT; ++co) {
        float* op = out + (size_t)((half * 8 + co) * NE + e) * LOUTN + t0;
        if (full) {
            #pragma unroll
            for (int tt = 0; tt < TPT; ++tt) op[tt] = acc[co][tt];
        } else {
            #pragma unroll
            for (int tt = 0; tt < TPT; ++tt)
                if (t0 + tt < LOUTN) op[tt] = acc[co][tt];
        }
    }
}

extern "C" void kernel_launch(void* const* d_in, const int* in_sizes, int n_in,
                              void* d_out, int out_size, void* d_ws, size_t ws_size,
                              hipStream_t stream)
{
    const float* x = (const float*)d_in[0];
    const float* W = (const float*)d_in[1];
    const float* b = (const float*)d_in[2];
    float* out     = (float*)d_out;

    float* Wr = (float*)d_ws;            // 36864 floats
    float* Br = Wr + NWREP;              // 384 floats

    repack_kernel<<<(NWREP + BLOCK - 1) / BLOCK, BLOCK, 0, stream>>>(W, b, Wr, Br);

    dim3 grid(NCHUNK, NE, 2);
    skel_conv_kernel<<<grid, BLOCK, 0, stream>>>(x, Wr, Br, out);
}

// Round 6
// 83.262 us; speedup vs baseline: 1.3541x; 1.3149x over previous
//
#include <hip/hip_runtime.h>

// SkeletalConv via MFMA: out[co,e,t] = sum_k (Wk x X)[co,t+shift] , 3 taps.
// x: (16, 25, 65536) f32, W: (48, 16, 16, 3) f32, b: (48, 16) f32
// out: (16, 24, 65533) f32
// out[co,e,t] = 0.5*sum_{j,ci,k} W[2e+j,co,ci,k]*x[ci,e+j,t+k] + 0.5*(b[2e,co]+b[2e+1,co])
//
// Formulation: per edge, K-dim kk=(ci,j) has size 32 = exactly one
// mfma_f32_16x16x32_bf16 per tap. A = bf16(0.5*W) repacked per-lane (d_ws),
// B = bf16(x) built in registers from 8 coalesced dword loads (uniform SGPR
// row bases + one per-lane voffset + immediate offsets). C accumulates in
// fp32 with the folded bias. A/B use the same (lane-group,slot)->kk
// enumeration so any internal k-permutation cancels.

#define NJ    25
#define LSEQ  65536
#define NE    24
#define LOUTN (LSEQ - 3 + 1)           // 65533
#define NWA   (NE * 3 * 64 * 4)        // 18432 packed dwords
#define NBR   (NE * 16)                // 384 folded biases

typedef __attribute__((ext_vector_type(8))) short bf16x8;
typedef __attribute__((ext_vector_type(4))) float f32x4;

static __device__ __forceinline__ unsigned short f2bf(float f) {
    unsigned u = __float_as_uint(f);
    u += 0x7FFFu + ((u >> 16) & 1u);   // round-to-nearest-even
    return (unsigned short)(u >> 16);
}

// Wa[((e*3+k)*64+l)*4+d] = pack(bf16(0.5*W[2e+j,co,ci,k]) for i=2d,2d+1)
//   with co=l&15, g=l>>4, kk=8g+i, ci=kk>>1, j=kk&1.
// Br[e*16+co] = 0.5*(b[2e,co]+b[2e+1,co])
__global__ void repack_kernel(const float* __restrict__ W, const float* __restrict__ b,
                              unsigned* __restrict__ Wa, float* __restrict__ Br)
{
    int idx = blockIdx.x * 256 + threadIdx.x;
    if (idx < NWA) {
        int d = idx & 3;
        int l = (idx >> 2) & 63;
        int k = (idx >> 8) % 3;
        int e = (idx >> 8) / 3;
        int g = l >> 4, co = l & 15;
        unsigned packed = 0;
        #pragma unroll
        for (int h = 0; h < 2; ++h) {
            int i  = 2 * d + h;
            int kk = 8 * g + i;
            int ci = kk >> 1, j = kk & 1;
            float w = 0.5f * W[(((2 * e + j) * 16 + co) * 16 + ci) * 3 + k];
            packed |= (unsigned)f2bf(w) << (16 * h);
        }
        Wa[idx] = packed;
    }
    if (idx < NBR) {
        int e = idx >> 4, co = idx & 15;
        Br[idx] = 0.5f * (b[(2 * e) * 16 + co] + b[(2 * e + 1) * 16 + co]);
    }
}

__global__ __launch_bounds__(256)
void skel_mfma_kernel(const float* __restrict__ x,
                      const unsigned* __restrict__ Wa,
                      const float* __restrict__ Br,
                      float* __restrict__ out)
{
    const int e  = blockIdx.y;
    const int wv = threadIdx.x >> 6;
    const int l  = threadIdx.x & 63;
    const int g  = l >> 4, lc = l & 15;

    // ---- A fragments (3 taps), per-lane prepacked ----
    union { uint4 q; unsigned u[4]; bf16x8 v; } A[3];
    #pragma unroll
    for (int k = 0; k < 3; ++k)
        A[k].q = *reinterpret_cast<const uint4*>(Wa + ((e * 3 + k) * 64 + l) * 4);

    const float4 bias = *reinterpret_cast<const float4*>(Br + e * 16 + g * 4);

    // ---- uniform row-base pointers (SGPR) + per-lane voffset ----
    // x row for (g,i): ci = 4g + (i>>1), joint = e + (i&1)
    // flat = ci*25*65536 + joint*65536 ; the 4g*25*65536 part lives in vbase.
    const float* xb[8];
    #pragma unroll
    for (int i = 0; i < 8; ++i)
        xb[i] = x + (size_t)((i >> 1) * NJ + e + (i & 1)) * LSEQ;

    const int vbase = g * (4 * NJ * LSEQ) + lc;     // elements
    const int ixmax = g * (4 * NJ * LSEQ) + (LSEQ - 1);
    const bool tail = (blockIdx.x == gridDim.x - 1);

    const int t0w = (blockIdx.x * 4 + wv) * 256;

    #pragma unroll 1
    for (int it = 0; it < 4; ++it) {
        const int tbase = t0w + it * 64;

        f32x4 C[4];
        #pragma unroll
        for (int tc = 0; tc < 4; ++tc) {
            C[tc][0] = bias.x; C[tc][1] = bias.y;
            C[tc][2] = bias.z; C[tc][3] = bias.w;
        }

        #pragma unroll
        for (int tc = 0; tc < 4; ++tc) {
            #pragma unroll
            for (int k = 0; k < 3; ++k) {
                const int cu = tbase + tc * 16 + k;
                float v[8];
                #pragma unroll
                for (int i = 0; i < 8; ++i) {
                    int ix = vbase + cu;
                    if (tail) ix = min(ix, ixmax);   // clamp col; affects only masked outputs
                    v[i] = xb[i][ix];
                }
                union { unsigned u[4]; bf16x8 v8; } B;
                #pragma unroll
                for (int d = 0; d < 4; ++d)
                    B.u[d] = (unsigned)f2bf(v[2 * d]) | ((unsigned)f2bf(v[2 * d + 1]) << 16);
                C[tc] = __builtin_amdgcn_mfma_f32_16x16x32_bf16(A[k].v, B.v8, C[tc], 0, 0, 0);
            }
        }

        // ---- store: C row = co = g*4+r, col = t = tbase+tc*16+lc ----
        #pragma unroll
        for (int tc = 0; tc < 4; ++tc) {
            const int t = tbase + tc * 16 + lc;
            if (t < LOUTN) {
                #pragma unroll
                for (int r = 0; r < 4; ++r)
                    out[(size_t)((g * 4 + r) * NE + e) * LOUTN + t] = C[tc][r];
            }
        }
    }
}

extern "C" void kernel_launch(void* const* d_in, const int* in_sizes, int n_in,
                              void* d_out, int out_size, void* d_ws, size_t ws_size,
                              hipStream_t stream)
{
    const float* x = (const float*)d_in[0];
    const float* W = (const float*)d_in[1];
    const float* b = (const float*)d_in[2];
    float* out     = (float*)d_out;

    unsigned* Wa = (unsigned*)d_ws;          // 18432 dwords
    float*    Br = (float*)(Wa + NWA);       // 384 floats

    repack_kernel<<<(NWA + 255) / 256, 256, 0, stream>>>(W, b, Wa, Br);

    dim3 grid(64, NE);                       // 64 blocks x 1024 t = 65536 >= 65533
    skel_mfma_kernel<<<grid, 256, 0, stream>>>(x, Wa, Br, out);
}